// Round 4
// baseline (430.226 us; speedup 1.0000x reference)
//
#include <hip/hip_runtime.h>

// MiniSTU: out[b,l,o] = sum_k sum_{s<=l} phi[l-s,k]*(x@Mp[k])[o] + (-1)^(l-s)-weighted Mm term
// Stage 1: Z[b][kk][o][s] = (x[b] @ M[kk])^T   (48 = 24 filters x 2 signs), bf16
// Stage 2: partial[b][kg][l][o] = sum_{kk in kg} sum_s ToepA[kk][lb-sc][l'][s'] * Z[b][kk][o][s]
// Reduce:  out = sum_kg partial

#define ZB_ 12582912  // Z elems per batch (48*256*1024)

typedef __attribute__((ext_vector_type(8))) short bf16x8;
typedef __attribute__((ext_vector_type(4))) float f32x4;

__device__ inline unsigned short f2bf(float f) {
    unsigned u = __float_as_uint(f);
    u += 0x7FFFu + ((u >> 16) & 1u);   // RNE
    return (unsigned short)(u >> 16);
}

// ---- prep: x (f32) -> xb (bf16) ---------------------------------------------
__global__ void k_prep_x(const float* __restrict__ x, unsigned short* __restrict__ xb) {
    int i = (blockIdx.x * 256 + threadIdx.x) * 4;
    float4 v = *(const float4*)(x + i);
    ushort4 o;
    o.x = f2bf(v.x); o.y = f2bf(v.y); o.z = f2bf(v.z); o.w = f2bf(v.w);
    *(ushort4*)(xb + i) = o;
}

// ---- prep: MbT[kk][o][i] = M(kk)[i][o] (bf16) -------------------------------
__global__ void k_transpose_M(const float* __restrict__ Mp, const float* __restrict__ Mm,
                              unsigned short* __restrict__ MbT) {
    __shared__ float tile[32][33];
    int kk = blockIdx.z;
    const float* src = ((kk < 24) ? Mp : Mm) + (size_t)((kk < 24) ? kk : kk - 24) * 65536;
    int i0 = blockIdx.x * 32, o0 = blockIdx.y * 32;
    int tx = threadIdx.x, ty = threadIdx.y;
    for (int j = 0; j < 4; ++j)
        tile[ty + j * 8][tx] = src[(i0 + ty + j * 8) * 256 + o0 + tx];
    __syncthreads();
    for (int j = 0; j < 4; ++j)
        MbT[(size_t)kk * 65536 + (o0 + ty + j * 8) * 256 + i0 + tx] = f2bf(tile[tx][ty + j * 8]);
}

// ---- prep: ToepA[kk][d][i][j] = sgn*phi[d*64+i-j][k]  (0 if t<0), bf16 -------
__global__ void k_prep_toep(const float* __restrict__ phi, unsigned short* __restrict__ ToepA) {
    int kk = blockIdx.x;   // 48
    int d  = blockIdx.y;   // 16
    int k = (kk < 24) ? kk : kk - 24;
    int row = threadIdx.x >> 2, c0 = (threadIdx.x & 3) * 16;
    unsigned short* dst = ToepA + ((size_t)kk * 16 + d) * 4096 + row * 64 + c0;
#pragma unroll
    for (int q = 0; q < 4; ++q) {
        ushort4 ov;
        unsigned short e[4];
#pragma unroll
        for (int ee = 0; ee < 4; ++ee) {
            int j = c0 + q * 4 + ee;
            int t = d * 64 + row - j;          // always <= 1023
            float v = 0.f;
            if (t >= 0) {
                v = phi[t * 24 + k];
                if (kk >= 24 && (t & 1)) v = -v;
            }
            e[ee] = f2bf(v);
        }
        ov.x = e[0]; ov.y = e[1]; ov.z = e[2]; ov.w = e[3];
        *(ushort4*)(dst + q * 4) = ov;
    }
}

// ---- stage 1: grid (8 m-tiles, 96 = 48kk x 2 o-halves, g batches), 256 thr ---
// __launch_bounds__(256, 2): allow up to ~256 VGPR so acc+prefetch stay in regs.
__global__ __launch_bounds__(256, 2) void k_stage1(const unsigned short* __restrict__ xb0,
                                                   const unsigned short* __restrict__ MbT,
                                                   unsigned short* __restrict__ Z) {
    __shared__ unsigned short Al[128 * 40];
    __shared__ unsigned short Bl[128 * 40];
    int tid = threadIdx.x, lane = tid & 63, w = tid >> 6;
    int wm = w >> 1, wn = w & 1;
    int m0 = blockIdx.x * 128;
    int kk = blockIdx.y >> 1;
    int o0 = (blockIdx.y & 1) * 128;
    int b  = blockIdx.z;
    const unsigned short* xb_b = xb0 + (size_t)b * 262144;
    unsigned short* Zb = Z + (size_t)b * ZB_;
    const unsigned short* Bsrc = MbT + (size_t)kk * 65536;
    int l16 = lane & 15, kofs = (lane >> 4) * 8;

    f32x4 acc[4][4];
    for (int i = 0; i < 4; ++i)
        for (int j = 0; j < 4; ++j) {
            acc[i][j][0] = 0.f; acc[i][j][1] = 0.f; acc[i][j][2] = 0.f; acc[i][j][3] = 0.f;
        }

    int row = tid >> 1, half = tid & 1;
    const unsigned short* asrc = xb_b + (m0 + row) * 256 + half * 16;
    const unsigned short* bsrc = Bsrc + (o0 + row) * 256 + half * 16;
    uint4 va0 = *(const uint4*)(asrc);
    uint4 va1 = *(const uint4*)(asrc + 8);
    uint4 vb0 = *(const uint4*)(bsrc);
    uint4 vb1 = *(const uint4*)(bsrc + 8);

    for (int ko = 0; ko < 8; ++ko) {
        __syncthreads();
        *(uint4*)(Al + row * 40 + half * 16)     = va0;
        *(uint4*)(Al + row * 40 + half * 16 + 8) = va1;
        *(uint4*)(Bl + row * 40 + half * 16)     = vb0;
        *(uint4*)(Bl + row * 40 + half * 16 + 8) = vb1;
        __syncthreads();
        if (ko < 7) {
            va0 = *(const uint4*)(asrc + (ko + 1) * 32);
            va1 = *(const uint4*)(asrc + (ko + 1) * 32 + 8);
            vb0 = *(const uint4*)(bsrc + (ko + 1) * 32);
            vb1 = *(const uint4*)(bsrc + (ko + 1) * 32 + 8);
        }
        bf16x8 af[4], bfv[4];
        for (int mi = 0; mi < 4; ++mi)
            af[mi] = *(const bf16x8*)(Al + (wm * 64 + mi * 16 + l16) * 40 + kofs);
        for (int ni = 0; ni < 4; ++ni)
            bfv[ni] = *(const bf16x8*)(Bl + (wn * 64 + ni * 16 + l16) * 40 + kofs);
        for (int mi = 0; mi < 4; ++mi)
            for (int ni = 0; ni < 4; ++ni)
                acc[mi][ni] = __builtin_amdgcn_mfma_f32_16x16x32_bf16(af[mi], bfv[ni], acc[mi][ni], 0, 0, 0);
    }

    int r4 = (lane >> 4) * 4;
    for (int mi = 0; mi < 4; ++mi) {
        int sbase = m0 + wm * 64 + mi * 16 + r4;
        for (int ni = 0; ni < 4; ++ni) {
            int o = o0 + wn * 64 + ni * 16 + l16;
            ushort4 pk;
            pk.x = f2bf(acc[mi][ni][0]); pk.y = f2bf(acc[mi][ni][1]);
            pk.z = f2bf(acc[mi][ni][2]); pk.w = f2bf(acc[mi][ni][3]);
            *(ushort4*)(Zb + (size_t)kk * 262144 + (size_t)o * 1024 + sbase) = pk;
        }
    }
}

// ---- stage 2: grid (8 diag-pairs, 2 o-tiles x g batches, kg), 256 thr --------
// Block pr handles l-tiles {pr, 15-pr}: exactly 17 s-chunks -> uniform work.
// __launch_bounds__(256, 2): prevents the 64-VGPR cap that spilled zv[]/av[]
// to scratch (was ~1.7 GB of scratch round-trip traffic per dispatch).
__global__ __launch_bounds__(256, 2) void k_stage2(const unsigned short* __restrict__ Z,
                                                   const unsigned short* __restrict__ ToepA,
                                                   float* __restrict__ partial, int kkpg) {
    __shared__ unsigned short Al[64 * 72];   // [64 l][64 s] pad->72
    __shared__ unsigned short Zl[128 * 72];  // [128 o][64 s] pad->72
    int tid = threadIdx.x, lane = tid & 63, w = tid >> 6;
    int wm = w >> 1, wn = w & 1;
    int pr = blockIdx.x;
    int o0 = (blockIdx.y & 1) * 128;
    int b  = blockIdx.y >> 1;
    int kgi = blockIdx.z;
    int kk0 = kgi * kkpg;
    int l16 = lane & 15, kofs = (lane >> 4) * 8;
    int r0 = tid >> 3, c8 = (tid & 7) * 8;

    const unsigned short* Zb = Z + (size_t)b * ZB_;
    float* pb = partial + ((size_t)b * gridDim.z + kgi) * 262144;

    for (int half = 0; half < 2; ++half) {
        int lb = half ? (15 - pr) : pr;
        int l0 = lb * 64;
        int nch = lb + 1;
        int total = kkpg * nch;

        f32x4 acc[2][4];
        for (int i = 0; i < 2; ++i)
            for (int j = 0; j < 4; ++j) {
                acc[i][j][0] = 0.f; acc[i][j][1] = 0.f; acc[i][j][2] = 0.f; acc[i][j][3] = 0.f;
            }

        uint4 zv[4], av[2];
        {   // preload chunk 0: kkx=0, sc=0, d=lb
#pragma unroll
            for (int it = 0; it < 4; ++it)
                zv[it] = *(const uint4*)(Zb + (size_t)kk0 * 262144 + (size_t)(o0 + it * 32 + r0) * 1024 + c8);
#pragma unroll
            for (int it = 0; it < 2; ++it)
                av[it] = *(const uint4*)(ToepA + ((size_t)kk0 * 16 + lb) * 4096 + (it * 32 + r0) * 64 + c8);
        }

        int sc = 0, kkx = 0;
        for (int j = 0; j < total; ++j) {
            __syncthreads();
#pragma unroll
            for (int it = 0; it < 4; ++it)
                *(uint4*)(Zl + (it * 32 + r0) * 72 + c8) = zv[it];
#pragma unroll
            for (int it = 0; it < 2; ++it)
                *(uint4*)(Al + (it * 32 + r0) * 72 + c8) = av[it];
            __syncthreads();

            int scn = sc + 1, kkn = kkx;
            if (scn == nch) { scn = 0; kkn = kkx + 1; }
            if (j + 1 < total) {   // prefetch next chunk (overlaps MFMA below)
                int kka = kk0 + kkn, d = lb - scn;
#pragma unroll
                for (int it = 0; it < 4; ++it)
                    zv[it] = *(const uint4*)(Zb + (size_t)kka * 262144 + (size_t)(o0 + it * 32 + r0) * 1024 + scn * 64 + c8);
#pragma unroll
                for (int it = 0; it < 2; ++it)
                    av[it] = *(const uint4*)(ToepA + ((size_t)kka * 16 + d) * 4096 + (it * 32 + r0) * 64 + c8);
            }

#pragma unroll
            for (int ks = 0; ks < 2; ++ks) {
                int ko = ks * 32 + kofs;
                bf16x8 af[2], bfv[4];
                for (int mi = 0; mi < 2; ++mi)
                    af[mi] = *(const bf16x8*)(Al + (wm * 32 + mi * 16 + l16) * 72 + ko);
                for (int ni = 0; ni < 4; ++ni)
                    bfv[ni] = *(const bf16x8*)(Zl + (wn * 64 + ni * 16 + l16) * 72 + ko);
                for (int mi = 0; mi < 2; ++mi)
                    for (int ni = 0; ni < 4; ++ni)
                        acc[mi][ni] = __builtin_amdgcn_mfma_f32_16x16x32_bf16(af[mi], bfv[ni], acc[mi][ni], 0, 0, 0);
            }
            sc = scn; kkx = kkn;
        }

        int r4 = (lane >> 4) * 4;
        for (int mi = 0; mi < 2; ++mi) {
            int l = l0 + wm * 32 + mi * 16 + r4;
            for (int ni = 0; ni < 4; ++ni) {
                int o = o0 + wn * 64 + ni * 16 + l16;
                float* dst = pb + (size_t)l * 256 + o;
                dst[0]   = acc[mi][ni][0];
                dst[256] = acc[mi][ni][1];
                dst[512] = acc[mi][ni][2];
                dst[768] = acc[mi][ni][3];
            }
        }
    }
}

// ---- reduce: out[b][l][o] = sum_kg partial[b][kg][l][o] ----------------------
__global__ void k_reduce(const float* __restrict__ partial, float* __restrict__ outg, int kg) {
    const float* pb = partial + (size_t)blockIdx.y * kg * 262144;
    int i = (blockIdx.x * 256 + threadIdx.x) * 4;
    float4 s = *(const float4*)(pb + i);
    for (int kgi = 1; kgi < kg; ++kgi) {
        float4 v = *(const float4*)(pb + (size_t)kgi * 262144 + i);
        s.x += v.x; s.y += v.y; s.z += v.z; s.w += v.w;
    }
    *(float4*)(outg + (size_t)blockIdx.y * 262144 + i) = s;
}

extern "C" void kernel_launch(void* const* d_in, const int* in_sizes, int n_in,
                              void* d_out, int out_size, void* d_ws, size_t ws_size,
                              hipStream_t stream) {
    const float* x   = (const float*)d_in[0];   // [4,1024,256]
    const float* phi = (const float*)d_in[1];   // [1024,24]
    const float* Mp  = (const float*)d_in[2];   // [24,256,256]
    const float* Mm  = (const float*)d_in[3];   // [24,256,256]
    float* out = (float*)d_out;                 // [4,1024,256]

    char* ws = (char*)d_ws;
    unsigned short* xb    = (unsigned short*)(ws);             // 2,097,152 B
    unsigned short* MbT   = (unsigned short*)(ws + 2097152);   // 6,291,456 B
    unsigned short* ToepA = (unsigned short*)(ws + 8388608);   // 6,291,456 B
    unsigned short* Zbuf  = (unsigned short*)(ws + 14680064);  // g * 25,165,824 B
    const size_t fixed = 14680064;

    // pick batch-group size g and split-K kg to fit ws_size
    int g = 4, kg = 12;
    auto need = [&](int gg, int kk) {
        return fixed + (size_t)gg * 25165824 + (size_t)gg * (size_t)kk * 1048576;
    };
    if (need(4, 12) > ws_size) {
        g = 2;
        if (need(2, 12) > ws_size) {
            g = 1;
            if (need(1, 12) > ws_size) kg = 6;   // 46,137,344 B total
        }
    }
    float* partial = (float*)(ws + fixed + (size_t)g * 25165824);

    k_prep_x<<<dim3(1024), dim3(256), 0, stream>>>(x, xb);
    k_transpose_M<<<dim3(8, 8, 48), dim3(32, 8), 0, stream>>>(Mp, Mm, MbT);
    k_prep_toep<<<dim3(48, 16), dim3(256), 0, stream>>>(phi, ToepA);

    for (int b0 = 0; b0 < 4; b0 += g) {
        k_stage1<<<dim3(8, 96, g), dim3(256), 0, stream>>>(xb + (size_t)b0 * 262144, MbT, Zbuf);
        k_stage2<<<dim3(8, 2 * g, kg), dim3(256), 0, stream>>>(Zbuf, ToepA, partial, 48 / kg);
        k_reduce<<<dim3(256, g), dim3(256), 0, stream>>>(partial, out + (size_t)b0 * 262144, kg);
    }
}

// Round 5
// 183.775 us; speedup vs baseline: 2.3410x; 2.3410x over previous
//
#include <hip/hip_runtime.h>

// MiniSTU: out[b,l,o] = sum_k sum_{s<=l} phi[l-s,k]*(x@Mp[k])[o] + (-1)^(l-s)-weighted Mm term
// Stage 1: Z[b][kk][o][s]  (s pre-swizzled: s ^= (o&7)<<3 within 64-chunks), bf16
// Stage 2: 128l x 128o tiles, global_load_lds double-buffered, Toeplitz MFMA GEMM
// Reduce:  out = sum_kg partial

#define ZB_ 12582912  // Z elems per batch (48*256*1024)

typedef __attribute__((ext_vector_type(8))) short bf16x8;
typedef __attribute__((ext_vector_type(4))) float f32x4;

__device__ inline unsigned short f2bf(float f) {
    unsigned u = __float_as_uint(f);
    u += 0x7FFFu + ((u >> 16) & 1u);   // RNE
    return (unsigned short)(u >> 16);
}

__device__ inline void gl16(const unsigned short* g, unsigned short* l) {
    __builtin_amdgcn_global_load_lds((const __attribute__((address_space(1))) void*)g,
                                     (__attribute__((address_space(3))) void*)l, 16, 0, 0);
}

// ---- prep: x (f32) -> xb (bf16) ---------------------------------------------
__global__ void k_prep_x(const float* __restrict__ x, unsigned short* __restrict__ xb) {
    int i = (blockIdx.x * 256 + threadIdx.x) * 4;
    float4 v = *(const float4*)(x + i);
    ushort4 o;
    o.x = f2bf(v.x); o.y = f2bf(v.y); o.z = f2bf(v.z); o.w = f2bf(v.w);
    *(ushort4*)(xb + i) = o;
}

// ---- prep: MbT[kk][o][i] = M(kk)[i][o] (bf16) -------------------------------
__global__ void k_transpose_M(const float* __restrict__ Mp, const float* __restrict__ Mm,
                              unsigned short* __restrict__ MbT) {
    __shared__ float tile[32][33];
    int kk = blockIdx.z;
    const float* src = ((kk < 24) ? Mp : Mm) + (size_t)((kk < 24) ? kk : kk - 24) * 65536;
    int i0 = blockIdx.x * 32, o0 = blockIdx.y * 32;
    int tx = threadIdx.x, ty = threadIdx.y;
    for (int j = 0; j < 4; ++j)
        tile[ty + j * 8][tx] = src[(i0 + ty + j * 8) * 256 + o0 + tx];
    __syncthreads();
    for (int j = 0; j < 4; ++j)
        MbT[(size_t)kk * 65536 + (o0 + ty + j * 8) * 256 + i0 + tx] = f2bf(tile[tx][ty + j * 8]);
}

// ---- prep: ToepA[kk][didx] 128x64 tiles, col pre-swizzled --------------------
// ToepA[kk][didx][i][j'] = sgn*phi[(didx-1)*64 + i - j][k],  j' = j ^ ((i&7)<<3)
__global__ void k_prep_toep(const float* __restrict__ phi, unsigned short* __restrict__ ToepA) {
    int kk = blockIdx.x;        // 48
    int dm = (int)blockIdx.y - 1;  // d64 in [-1, 14]
    int k = (kk < 24) ? kk : kk - 24;
    int tid = threadIdx.x;
    int i = tid >> 1, j0 = (tid & 1) * 32;
    unsigned short* dst = ToepA + ((size_t)kk * 16 + (dm + 1)) * 8192 + i * 64;
    int sw = (i & 7) << 3;
#pragma unroll
    for (int q = 0; q < 8; ++q) {
        int j = j0 + q * 4;
        unsigned short e[4];
#pragma unroll
        for (int ee = 0; ee < 4; ++ee) {
            int t = dm * 64 + i - (j + ee);
            float v = 0.f;
            if (t >= 0 && t < 1024) {
                v = phi[t * 24 + k];
                if (kk >= 24 && (t & 1)) v = -v;
            }
            e[ee] = f2bf(v);
        }
        ushort4 ov; ov.x = e[0]; ov.y = e[1]; ov.z = e[2]; ov.w = e[3];
        *(ushort4*)(dst + (j ^ sw)) = ov;   // j%8 in {0,4}: stays in one 8-group
    }
}

// ---- stage 1: grid (8 m-tiles, 96 = 48kk x 2 o-halves, g batches), 256 thr ---
__global__ __launch_bounds__(256, 2) void k_stage1(const unsigned short* __restrict__ xb0,
                                                   const unsigned short* __restrict__ MbT,
                                                   unsigned short* __restrict__ Z) {
    __shared__ unsigned short Al[128 * 40];
    __shared__ unsigned short Bl[128 * 40];
    int tid = threadIdx.x, lane = tid & 63, w = tid >> 6;
    int wm = w >> 1, wn = w & 1;
    int m0 = blockIdx.x * 128;
    int kk = blockIdx.y >> 1;
    int o0 = (blockIdx.y & 1) * 128;
    int b  = blockIdx.z;
    const unsigned short* xb_b = xb0 + (size_t)b * 262144;
    unsigned short* Zb = Z + (size_t)b * ZB_;
    const unsigned short* Bsrc = MbT + (size_t)kk * 65536;
    int l16 = lane & 15, kofs = (lane >> 4) * 8;

    f32x4 acc[4][4];
    for (int i = 0; i < 4; ++i)
        for (int j = 0; j < 4; ++j) {
            acc[i][j][0] = 0.f; acc[i][j][1] = 0.f; acc[i][j][2] = 0.f; acc[i][j][3] = 0.f;
        }

    int row = tid >> 1, half = tid & 1;
    const unsigned short* asrc = xb_b + (m0 + row) * 256 + half * 16;
    const unsigned short* bsrc = Bsrc + (o0 + row) * 256 + half * 16;
    uint4 va0 = *(const uint4*)(asrc);
    uint4 va1 = *(const uint4*)(asrc + 8);
    uint4 vb0 = *(const uint4*)(bsrc);
    uint4 vb1 = *(const uint4*)(bsrc + 8);

    for (int ko = 0; ko < 8; ++ko) {
        __syncthreads();
        *(uint4*)(Al + row * 40 + half * 16)     = va0;
        *(uint4*)(Al + row * 40 + half * 16 + 8) = va1;
        *(uint4*)(Bl + row * 40 + half * 16)     = vb0;
        *(uint4*)(Bl + row * 40 + half * 16 + 8) = vb1;
        __syncthreads();
        if (ko < 7) {
            va0 = *(const uint4*)(asrc + (ko + 1) * 32);
            va1 = *(const uint4*)(asrc + (ko + 1) * 32 + 8);
            vb0 = *(const uint4*)(bsrc + (ko + 1) * 32);
            vb1 = *(const uint4*)(bsrc + (ko + 1) * 32 + 8);
        }
        bf16x8 af[4], bfv[4];
        for (int mi = 0; mi < 4; ++mi)
            af[mi] = *(const bf16x8*)(Al + (wm * 64 + mi * 16 + l16) * 40 + kofs);
        for (int ni = 0; ni < 4; ++ni)
            bfv[ni] = *(const bf16x8*)(Bl + (wn * 64 + ni * 16 + l16) * 40 + kofs);
        for (int mi = 0; mi < 4; ++mi)
            for (int ni = 0; ni < 4; ++ni)
                acc[mi][ni] = __builtin_amdgcn_mfma_f32_16x16x32_bf16(af[mi], bfv[ni], acc[mi][ni], 0, 0, 0);
    }

    // store Z with s pre-swizzled by (o&7)<<3 (within 64-chunk; sbase%8 in {0,4})
    int r4 = (lane >> 4) * 4;
    for (int mi = 0; mi < 4; ++mi) {
        int sbase = m0 + wm * 64 + mi * 16 + r4;
        for (int ni = 0; ni < 4; ++ni) {
            int o = o0 + wn * 64 + ni * 16 + l16;
            ushort4 pk;
            pk.x = f2bf(acc[mi][ni][0]); pk.y = f2bf(acc[mi][ni][1]);
            pk.z = f2bf(acc[mi][ni][2]); pk.w = f2bf(acc[mi][ni][3]);
            *(ushort4*)(Zb + (size_t)kk * 262144 + (size_t)o * 1024 + (sbase ^ ((o & 7) << 3))) = pk;
        }
    }
}

// ---- stage 2: grid (4 diag-pairs, 2 o-tiles x g batches, kg), 256 thr --------
// Block pr handles l-tiles(128) {pr, 7-pr}: 18 s-chunks total -> uniform work.
// Chunk: A[128l][64s] + Z[128o][64s] staged via global_load_lds (2-phase dbuf).
__global__ __launch_bounds__(256, 2) void k_stage2(const unsigned short* __restrict__ Z,
                                                   const unsigned short* __restrict__ ToepA,
                                                   float* __restrict__ partial, int kkpg) {
    __shared__ unsigned short lds[2][16384];  // [buf][ A 8192 | Z 8192 ]  = 64 KB
    int tid = threadIdx.x, lane = tid & 63, w = tid >> 6;
    int wm = w >> 1, wn = w & 1;
    int pr = blockIdx.x;
    int o0 = (blockIdx.y & 1) * 128;
    int b  = blockIdx.y >> 1;
    int kgi = blockIdx.z;
    int kk0 = kgi * kkpg;
    int l16 = lane & 15, kofs = (lane >> 4) * 8;
    int sw = (l16 & 7) << 3;
    int r8 = lane >> 3, cg = lane & 7;

    const unsigned short* Zb = Z + (size_t)b * ZB_;
    float* pb = partial + ((size_t)b * gridDim.z + kgi) * 262144;

    // per-thread invariant staging offsets (issue q covers rows q*32 + w*8 + r8)
    int arow[4], zrow[4], lofs[4];
#pragma unroll
    for (int q = 0; q < 4; ++q) {
        int rr = q * 32 + w * 8 + r8;
        arow[q] = rr * 64 + cg * 8;                       // within ToepA tile
        zrow[q] = (o0 + rr) * 1024 + cg * 8;              // within Zb[kk]
        lofs[q] = q * 2048 + w * 512;                     // wave-uniform LDS (shorts)
    }

    for (int half = 0; half < 2; ++half) {
        int lb = half ? (7 - pr) : pr;
        int l0 = lb * 128;
        int nch = 2 * lb + 2;
        int total = kkpg * nch;

        f32x4 acc[4][4];
        for (int i = 0; i < 4; ++i)
            for (int j = 0; j < 4; ++j) {
                acc[i][j][0] = 0.f; acc[i][j][1] = 0.f; acc[i][j][2] = 0.f; acc[i][j][3] = 0.f;
            }

        // prologue: stage chunk 0 (kkx=0, sc=0 -> didx = 2lb+1) into buf 0
        {
            const unsigned short* gA = ToepA + ((size_t)kk0 * 16 + (2 * lb + 1)) * 8192;
            const unsigned short* gZ = Zb + (size_t)kk0 * 262144;
            unsigned short* lA = &lds[0][0];
            unsigned short* lZ = &lds[0][8192];
#pragma unroll
            for (int q = 0; q < 4; ++q) {
                gl16(gA + arow[q], lA + lofs[q]);
                gl16(gZ + zrow[q], lZ + lofs[q]);
            }
        }
        __syncthreads();

        int sc = 0, kkx = 0, buf = 0;
        for (int j = 0; j < total; ++j) {
            // issue next chunk's stage into buf^1 (latency hides under MFMA)
            int scn = sc + 1, kkn = kkx;
            if (scn == nch) { scn = 0; kkn = kkx + 1; }
            if (j + 1 < total) {
                int kka = kk0 + kkn;
                const unsigned short* gA = ToepA + ((size_t)kka * 16 + (2 * lb - scn + 1)) * 8192;
                const unsigned short* gZ = Zb + (size_t)kka * 262144 + scn * 64;
                unsigned short* lA = &lds[buf ^ 1][0];
                unsigned short* lZ = &lds[buf ^ 1][8192];
#pragma unroll
                for (int q = 0; q < 4; ++q) {
                    gl16(gA + arow[q], lA + lofs[q]);
                    gl16(gZ + zrow[q], lZ + lofs[q]);
                }
            }

            // compute current chunk from lds[buf]
            const unsigned short* Abase = &lds[buf][0];
            const unsigned short* Zbase = &lds[buf][8192];
#pragma unroll
            for (int ks = 0; ks < 2; ++ks) {
                int koX = (ks * 32 + kofs) ^ sw;
                bf16x8 af[4], bfv[4];
#pragma unroll
                for (int mi = 0; mi < 4; ++mi)
                    af[mi] = *(const bf16x8*)(Abase + (wm * 64 + mi * 16 + l16) * 64 + koX);
#pragma unroll
                for (int ni = 0; ni < 4; ++ni)
                    bfv[ni] = *(const bf16x8*)(Zbase + (wn * 64 + ni * 16 + l16) * 64 + koX);
#pragma unroll
                for (int mi = 0; mi < 4; ++mi)
#pragma unroll
                    for (int ni = 0; ni < 4; ++ni)
                        acc[mi][ni] = __builtin_amdgcn_mfma_f32_16x16x32_bf16(af[mi], bfv[ni], acc[mi][ni], 0, 0, 0);
            }
            __syncthreads();   // drains next-stage loads; guards LDS reuse
            sc = scn; kkx = kkn; buf ^= 1;
        }

        int r4 = (lane >> 4) * 4;
        for (int mi = 0; mi < 4; ++mi) {
            int l = l0 + wm * 64 + mi * 16 + r4;
            for (int ni = 0; ni < 4; ++ni) {
                int o = o0 + wn * 64 + ni * 16 + l16;
                float* dst = pb + (size_t)l * 256 + o;
                dst[0]   = acc[mi][ni][0];
                dst[256] = acc[mi][ni][1];
                dst[512] = acc[mi][ni][2];
                dst[768] = acc[mi][ni][3];
            }
        }
    }
}

// ---- reduce: out[b][l][o] = sum_kg partial[b][kg][l][o] ----------------------
__global__ void k_reduce(const float* __restrict__ partial, float* __restrict__ outg, int kg) {
    const float* pb = partial + (size_t)blockIdx.y * kg * 262144;
    int i = (blockIdx.x * 256 + threadIdx.x) * 4;
    float4 s = *(const float4*)(pb + i);
    for (int kgi = 1; kgi < kg; ++kgi) {
        float4 v = *(const float4*)(pb + (size_t)kgi * 262144 + i);
        s.x += v.x; s.y += v.y; s.z += v.z; s.w += v.w;
    }
    *(float4*)(outg + (size_t)blockIdx.y * 262144 + i) = s;
}

extern "C" void kernel_launch(void* const* d_in, const int* in_sizes, int n_in,
                              void* d_out, int out_size, void* d_ws, size_t ws_size,
                              hipStream_t stream) {
    const float* x   = (const float*)d_in[0];   // [4,1024,256]
    const float* phi = (const float*)d_in[1];   // [1024,24]
    const float* Mp  = (const float*)d_in[2];   // [24,256,256]
    const float* Mm  = (const float*)d_in[3];   // [24,256,256]
    float* out = (float*)d_out;                 // [4,1024,256]

    char* ws = (char*)d_ws;
    unsigned short* xb    = (unsigned short*)(ws);             //  2,097,152 B
    unsigned short* MbT   = (unsigned short*)(ws + 2097152);   //  6,291,456 B
    unsigned short* ToepA = (unsigned short*)(ws + 8388608);   // 12,582,912 B (48*16 tiles 128x64)
    unsigned short* Zbuf  = (unsigned short*)(ws + 20971520);  // g * 25,165,824 B
    const size_t fixed = 20971520;

    int g = 4, kg = 12;
    auto need = [&](int gg, int kk) {
        return fixed + (size_t)gg * 25165824 + (size_t)gg * (size_t)kk * 1048576;
    };
    if (need(4, 12) > ws_size) {
        g = 2;
        if (need(2, 12) > ws_size) {
            g = 1;
            if (need(1, 12) > ws_size) kg = 6;
        }
    }
    float* partial = (float*)(ws + fixed + (size_t)g * 25165824);

    k_prep_x<<<dim3(1024), dim3(256), 0, stream>>>(x, xb);
    k_transpose_M<<<dim3(8, 8, 48), dim3(32, 8), 0, stream>>>(Mp, Mm, MbT);
    k_prep_toep<<<dim3(48, 16), dim3(256), 0, stream>>>(phi, ToepA);

    for (int b0 = 0; b0 < 4; b0 += g) {
        k_stage1<<<dim3(8, 96, g), dim3(256), 0, stream>>>(xb + (size_t)b0 * 262144, MbT, Zbuf);
        k_stage2<<<dim3(4, 2 * g, kg), dim3(256), 0, stream>>>(Zbuf, ToepA, partial, 48 / kg);
        k_reduce<<<dim3(256, g), dim3(256), 0, stream>>>(partial, out + (size_t)b0 * 262144, kg);
    }
}

// Round 6
// 179.252 us; speedup vs baseline: 2.4001x; 1.0252x over previous
//
#include <hip/hip_runtime.h>

// MiniSTU: out[b,l,o] = sum_k sum_{s<=l} phi[l-s,k]*(x@Mp[k])[o] + (-1)^(l-s)-weighted Mm term
// Stage 1: Z[b][kk][o][s]  (s pre-swizzled), gl16+dbuf MFMA GEMM
// Stage 2: 128l x 128o tiles, gl16+dbuf Toeplitz MFMA GEMM, kg-way split-K
// All LDS staging: linear dest + pre-swizzled global source + XOR on ds_read.

#define ZB_ 12582912  // Z elems per batch (48*256*1024)

typedef __attribute__((ext_vector_type(8))) short bf16x8;
typedef __attribute__((ext_vector_type(4))) float f32x4;

__device__ inline unsigned short f2bf(float f) {
    unsigned u = __float_as_uint(f);
    u += 0x7FFFu + ((u >> 16) & 1u);   // RNE
    return (unsigned short)(u >> 16);
}

__device__ inline void gl16(const unsigned short* g, unsigned short* l) {
    __builtin_amdgcn_global_load_lds((const __attribute__((address_space(1))) void*)g,
                                     (__attribute__((address_space(3))) void*)l, 16, 0, 0);
}

// ---- prep: x (f32) -> xb (bf16), i pre-swizzled within 64-chunks by (s&7)<<3 -
__global__ void k_prep_x(const float* __restrict__ x, unsigned short* __restrict__ xb) {
    int i = (blockIdx.x * 256 + threadIdx.x) * 4;
    float4 v = *(const float4*)(x + i);
    ushort4 o;
    o.x = f2bf(v.x); o.y = f2bf(v.y); o.z = f2bf(v.z); o.w = f2bf(v.w);
    int row = i >> 8, col = i & 255;
    int dst = (row << 8) | (col & 192) | ((col & 63) ^ ((row & 7) << 3));
    *(ushort4*)(xb + dst) = o;
}

// ---- prep: MbT[kk][o][i'] = M(kk)[i][o], i pre-swizzled by (o&7)<<3 ----------
__global__ void k_transpose_M(const float* __restrict__ Mp, const float* __restrict__ Mm,
                              unsigned short* __restrict__ MbT) {
    __shared__ float tile[32][33];
    int kk = blockIdx.z;
    const float* src = ((kk < 24) ? Mp : Mm) + (size_t)((kk < 24) ? kk : kk - 24) * 65536;
    int i0 = blockIdx.x * 32, o0 = blockIdx.y * 32;
    int tx = threadIdx.x, ty = threadIdx.y;
    for (int j = 0; j < 4; ++j)
        tile[ty + j * 8][tx] = src[(i0 + ty + j * 8) * 256 + o0 + tx];
    __syncthreads();
    for (int j = 0; j < 4; ++j) {
        int orow = o0 + ty + j * 8, i = i0 + tx;
        int ic = (i & 192) | ((i & 63) ^ ((orow & 7) << 3));
        MbT[(size_t)kk * 65536 + orow * 256 + ic] = f2bf(tile[tx][ty + j * 8]);
    }
}

// ---- prep: ToepA[kk][didx] 128x64 tiles, col pre-swizzled --------------------
// ToepA[kk][didx][i][j'] = sgn*phi[(didx-1)*64 + i - j][k],  j' = j ^ ((i&7)<<3)
__global__ void k_prep_toep(const float* __restrict__ phi, unsigned short* __restrict__ ToepA) {
    int kk = blockIdx.x;           // 48
    int dm = (int)blockIdx.y - 1;  // d64 in [-1, 14]
    int k = (kk < 24) ? kk : kk - 24;
    int tid = threadIdx.x;
    int i = tid >> 1, j0 = (tid & 1) * 32;
    unsigned short* dst = ToepA + ((size_t)kk * 16 + (dm + 1)) * 8192 + i * 64;
    int sw = (i & 7) << 3;
#pragma unroll
    for (int q = 0; q < 8; ++q) {
        int j = j0 + q * 4;
        unsigned short e[4];
#pragma unroll
        for (int ee = 0; ee < 4; ++ee) {
            int t = dm * 64 + i - (j + ee);
            float v = 0.f;
            if (t >= 0 && t < 1024) {
                v = phi[t * 24 + k];
                if (kk >= 24 && (t & 1)) v = -v;
            }
            e[ee] = f2bf(v);
        }
        ushort4 ov; ov.x = e[0]; ov.y = e[1]; ov.z = e[2]; ov.w = e[3];
        *(ushort4*)(dst + (j ^ sw)) = ov;
    }
}

// ---- stage 1: grid (8 m-tiles, 96 = 48kk x 2 o-halves, g batches), 256 thr ---
// gl16 double-buffered, 4 K-chunks of 64; XOR-swizzled ds_read.
__global__ __launch_bounds__(256, 2) void k_stage1(const unsigned short* __restrict__ xb0,
                                                   const unsigned short* __restrict__ MbT,
                                                   unsigned short* __restrict__ Z) {
    __shared__ unsigned short lds[2][16384];  // [buf][ A 8192 | B 8192 ]
    int tid = threadIdx.x, lane = tid & 63, w = tid >> 6;
    int wm = w >> 1, wn = w & 1;
    int m0 = blockIdx.x * 128;
    int kk = blockIdx.y >> 1;
    int o0 = (blockIdx.y & 1) * 128;
    int b  = blockIdx.z;
    const unsigned short* xb_b = xb0 + (size_t)b * 262144;
    unsigned short* Zb = Z + (size_t)b * ZB_;
    const unsigned short* Bsrc = MbT + (size_t)kk * 65536;
    int l16 = lane & 15, kofs = (lane >> 4) * 8;
    int sw = (l16 & 7) << 3;
    int r8 = lane >> 3, cg = lane & 7;

    int arow[4], brow[4], lofs[4];
#pragma unroll
    for (int q = 0; q < 4; ++q) {
        int rr = q * 32 + w * 8 + r8;
        arow[q] = (m0 + rr) * 256 + cg * 8;
        brow[q] = (o0 + rr) * 256 + cg * 8;
        lofs[q] = q * 2048 + w * 512;
    }

    f32x4 acc[4][4];
    for (int i = 0; i < 4; ++i)
        for (int j = 0; j < 4; ++j) {
            acc[i][j][0] = 0.f; acc[i][j][1] = 0.f; acc[i][j][2] = 0.f; acc[i][j][3] = 0.f;
        }

    // prologue: chunk 0 -> buf 0
#pragma unroll
    for (int q = 0; q < 4; ++q) {
        gl16(xb_b + arow[q], &lds[0][0] + lofs[q]);
        gl16(Bsrc + brow[q], &lds[0][8192] + lofs[q]);
    }
    __syncthreads();

    int buf = 0;
    for (int ko = 0; ko < 4; ++ko) {
        if (ko < 3) {
#pragma unroll
            for (int q = 0; q < 4; ++q) {
                gl16(xb_b + arow[q] + (ko + 1) * 64, &lds[buf ^ 1][0] + lofs[q]);
                gl16(Bsrc + brow[q] + (ko + 1) * 64, &lds[buf ^ 1][8192] + lofs[q]);
            }
        }
        const unsigned short* Abase = &lds[buf][0];
        const unsigned short* Bbase = &lds[buf][8192];
#pragma unroll
        for (int ks = 0; ks < 2; ++ks) {
            int koX = (ks * 32 + kofs) ^ sw;
            bf16x8 af[4], bfv[4];
#pragma unroll
            for (int mi = 0; mi < 4; ++mi)
                af[mi] = *(const bf16x8*)(Abase + (wm * 64 + mi * 16 + l16) * 64 + koX);
#pragma unroll
            for (int ni = 0; ni < 4; ++ni)
                bfv[ni] = *(const bf16x8*)(Bbase + (wn * 64 + ni * 16 + l16) * 64 + koX);
#pragma unroll
            for (int mi = 0; mi < 4; ++mi)
#pragma unroll
                for (int ni = 0; ni < 4; ++ni)
                    acc[mi][ni] = __builtin_amdgcn_mfma_f32_16x16x32_bf16(af[mi], bfv[ni], acc[mi][ni], 0, 0, 0);
        }
        __syncthreads();
        buf ^= 1;
    }

    // store Z with s pre-swizzled by (o&7)<<3 (within 64-chunk; sbase%8 in {0,4})
    int r4 = (lane >> 4) * 4;
    for (int mi = 0; mi < 4; ++mi) {
        int sbase = m0 + wm * 64 + mi * 16 + r4;
        for (int ni = 0; ni < 4; ++ni) {
            int o = o0 + wn * 64 + ni * 16 + l16;
            ushort4 pk;
            pk.x = f2bf(acc[mi][ni][0]); pk.y = f2bf(acc[mi][ni][1]);
            pk.z = f2bf(acc[mi][ni][2]); pk.w = f2bf(acc[mi][ni][3]);
            *(ushort4*)(Zb + (size_t)kk * 262144 + (size_t)o * 1024 + (sbase ^ ((o & 7) << 3))) = pk;
        }
    }
}

// ---- stage 2: grid (4 diag-pairs, 2 o-tiles x g batches, kg), 256 thr --------
// Block pr handles l-tiles(128) {pr, 7-pr}: 18 s-chunks total -> uniform work.
__global__ __launch_bounds__(256, 2) void k_stage2(const unsigned short* __restrict__ Z,
                                                   const unsigned short* __restrict__ ToepA,
                                                   float* __restrict__ partial, int kkpg) {
    __shared__ unsigned short lds[2][16384];  // [buf][ A 8192 | Z 8192 ]
    int tid = threadIdx.x, lane = tid & 63, w = tid >> 6;
    int wm = w >> 1, wn = w & 1;
    int pr = blockIdx.x;
    int o0 = (blockIdx.y & 1) * 128;
    int b  = blockIdx.y >> 1;
    int kgi = blockIdx.z;
    int kk0 = kgi * kkpg;
    int l16 = lane & 15, kofs = (lane >> 4) * 8;
    int sw = (l16 & 7) << 3;
    int r8 = lane >> 3, cg = lane & 7;

    const unsigned short* Zb = Z + (size_t)b * ZB_;
    float* pb = partial + ((size_t)b * gridDim.z + kgi) * 262144;

    int arow[4], zrow[4], lofs[4];
#pragma unroll
    for (int q = 0; q < 4; ++q) {
        int rr = q * 32 + w * 8 + r8;
        arow[q] = rr * 64 + cg * 8;
        zrow[q] = (o0 + rr) * 1024 + cg * 8;
        lofs[q] = q * 2048 + w * 512;
    }

    for (int half = 0; half < 2; ++half) {
        int lb = half ? (7 - pr) : pr;
        int l0 = lb * 128;
        int nch = 2 * lb + 2;
        int total = kkpg * nch;

        f32x4 acc[4][4];
        for (int i = 0; i < 4; ++i)
            for (int j = 0; j < 4; ++j) {
                acc[i][j][0] = 0.f; acc[i][j][1] = 0.f; acc[i][j][2] = 0.f; acc[i][j][3] = 0.f;
            }

        {   // prologue: chunk 0 (kkx=0, sc=0 -> didx = 2lb+1) into buf 0
            const unsigned short* gA = ToepA + ((size_t)kk0 * 16 + (2 * lb + 1)) * 8192;
            const unsigned short* gZ = Zb + (size_t)kk0 * 262144;
#pragma unroll
            for (int q = 0; q < 4; ++q) {
                gl16(gA + arow[q], &lds[0][0] + lofs[q]);
                gl16(gZ + zrow[q], &lds[0][8192] + lofs[q]);
            }
        }
        __syncthreads();

        int sc = 0, kkx = 0, buf = 0;
        for (int j = 0; j < total; ++j) {
            int scn = sc + 1, kkn = kkx;
            if (scn == nch) { scn = 0; kkn = kkx + 1; }
            if (j + 1 < total) {   // issue next chunk's stage into buf^1
                int kka = kk0 + kkn;
                const unsigned short* gA = ToepA + ((size_t)kka * 16 + (2 * lb - scn + 1)) * 8192;
                const unsigned short* gZ = Zb + (size_t)kka * 262144 + scn * 64;
#pragma unroll
                for (int q = 0; q < 4; ++q) {
                    gl16(gA + arow[q], &lds[buf ^ 1][0] + lofs[q]);
                    gl16(gZ + zrow[q], &lds[buf ^ 1][8192] + lofs[q]);
                }
            }

            const unsigned short* Abase = &lds[buf][0];
            const unsigned short* Zbase = &lds[buf][8192];
#pragma unroll
            for (int ks = 0; ks < 2; ++ks) {
                int koX = (ks * 32 + kofs) ^ sw;
                bf16x8 af[4], bfv[4];
#pragma unroll
                for (int mi = 0; mi < 4; ++mi)
                    af[mi] = *(const bf16x8*)(Abase + (wm * 64 + mi * 16 + l16) * 64 + koX);
#pragma unroll
                for (int ni = 0; ni < 4; ++ni)
                    bfv[ni] = *(const bf16x8*)(Zbase + (wn * 64 + ni * 16 + l16) * 64 + koX);
#pragma unroll
                for (int mi = 0; mi < 4; ++mi)
#pragma unroll
                    for (int ni = 0; ni < 4; ++ni)
                        acc[mi][ni] = __builtin_amdgcn_mfma_f32_16x16x32_bf16(af[mi], bfv[ni], acc[mi][ni], 0, 0, 0);
            }
            __syncthreads();
            sc = scn; kkx = kkn; buf ^= 1;
        }

        int r4 = (lane >> 4) * 4;
        for (int mi = 0; mi < 4; ++mi) {
            int l = l0 + wm * 64 + mi * 16 + r4;
            for (int ni = 0; ni < 4; ++ni) {
                int o = o0 + wn * 64 + ni * 16 + l16;
                float* dst = pb + (size_t)l * 256 + o;
                dst[0]   = acc[mi][ni][0];
                dst[256] = acc[mi][ni][1];
                dst[512] = acc[mi][ni][2];
                dst[768] = acc[mi][ni][3];
            }
        }
    }
}

// ---- reduce: out[b][l][o] = sum_kg partial[b][kg][l][o] ----------------------
__global__ void k_reduce(const float* __restrict__ partial, float* __restrict__ outg, int kg) {
    const float* pb = partial + (size_t)blockIdx.y * kg * 262144;
    int i = (blockIdx.x * 256 + threadIdx.x) * 4;
    float4 s = *(const float4*)(pb + i);
    for (int kgi = 1; kgi < kg; ++kgi) {
        float4 v = *(const float4*)(pb + (size_t)kgi * 262144 + i);
        s.x += v.x; s.y += v.y; s.z += v.z; s.w += v.w;
    }
    *(float4*)(outg + (size_t)blockIdx.y * 262144 + i) = s;
}

extern "C" void kernel_launch(void* const* d_in, const int* in_sizes, int n_in,
                              void* d_out, int out_size, void* d_ws, size_t ws_size,
                              hipStream_t stream) {
    const float* x   = (const float*)d_in[0];   // [4,1024,256]
    const float* phi = (const float*)d_in[1];   // [1024,24]
    const float* Mp  = (const float*)d_in[2];   // [24,256,256]
    const float* Mm  = (const float*)d_in[3];   // [24,256,256]
    float* out = (float*)d_out;                 // [4,1024,256]

    char* ws = (char*)d_ws;
    unsigned short* xb    = (unsigned short*)(ws);             //  2,097,152 B
    unsigned short* MbT   = (unsigned short*)(ws + 2097152);   //  6,291,456 B
    unsigned short* ToepA = (unsigned short*)(ws + 8388608);   // 12,582,912 B
    unsigned short* Zbuf  = (unsigned short*)(ws + 20971520);  // g * 25,165,824 B
    const size_t fixed = 20971520;

    // pick batch-group g and split-K kg (prefer 512-block uniform grid: g=4,kg=16)
    int g = 4, kg = 16;
    auto need = [&](int gg, int kk) {
        return fixed + (size_t)gg * 25165824 + (size_t)gg * (size_t)kk * 1048576;
    };
    if (need(4, 16) > ws_size) {
        kg = 12;
        if (need(4, 12) > ws_size) {
            g = 2; kg = 16;
            if (need(2, 16) > ws_size) {
                kg = 12;
                if (need(2, 12) > ws_size) {
                    g = 1; kg = 16;
                    if (need(1, 16) > ws_size) {
                        kg = 12;
                        if (need(1, 12) > ws_size) kg = 6;
                    }
                }
            }
        }
    }
    float* partial = (float*)(ws + fixed + (size_t)g * 25165824);

    k_prep_x<<<dim3(1024), dim3(256), 0, stream>>>(x, xb);
    k_transpose_M<<<dim3(8, 8, 48), dim3(32, 8), 0, stream>>>(Mp, Mm, MbT);
    k_prep_toep<<<dim3(48, 16), dim3(256), 0, stream>>>(phi, ToepA);

    for (int b0 = 0; b0 < 4; b0 += g) {
        k_stage1<<<dim3(8, 96, g), dim3(256), 0, stream>>>(xb + (size_t)b0 * 262144, MbT, Zbuf);
        k_stage2<<<dim3(4, 2 * g, kg), dim3(256), 0, stream>>>(Zbuf, ToepA, partial, 48 / kg);
        k_reduce<<<dim3(256, g), dim3(256), 0, stream>>>(partial, out + (size_t)b0 * 262144, kg);
    }
}

// Round 7
// 159.339 us; speedup vs baseline: 2.7001x; 1.1250x over previous
//
#include <hip/hip_runtime.h>

// MiniSTU: out[b,l,o] = sum_k sum_{s<=l} phi[l-s,k]*(x@Mp[k])[o] + (-1)^(l-s)-weighted Mm term
// Stage 1: Z[b][kk][o][s]  (s pre-swizzled), gl16+dbuf MFMA GEMM
// Stage 2: 128l x 128o tiles, gl16 counted-vmcnt pipeline (A 1-ahead, Z 2-ahead),
//          XCD-chunked block remap so pr-groups share an XCD's L2 for Z panels.
// All LDS staging: linear dest + pre-swizzled global source + XOR on ds_read.

#define ZB_ 12582912  // Z elems per batch (48*256*1024)

typedef __attribute__((ext_vector_type(8))) short bf16x8;
typedef __attribute__((ext_vector_type(4))) float f32x4;

__device__ inline unsigned short f2bf(float f) {
    unsigned u = __float_as_uint(f);
    u += 0x7FFFu + ((u >> 16) & 1u);   // RNE
    return (unsigned short)(u >> 16);
}

__device__ inline void gl16(const unsigned short* g, unsigned short* l) {
    __builtin_amdgcn_global_load_lds((const __attribute__((address_space(1))) void*)g,
                                     (__attribute__((address_space(3))) void*)l, 16, 0, 0);
}

// ---- prep: x (f32) -> xb (bf16), i pre-swizzled within 64-chunks by (s&7)<<3 -
__global__ void k_prep_x(const float* __restrict__ x, unsigned short* __restrict__ xb) {
    int i = (blockIdx.x * 256 + threadIdx.x) * 4;
    float4 v = *(const float4*)(x + i);
    ushort4 o;
    o.x = f2bf(v.x); o.y = f2bf(v.y); o.z = f2bf(v.z); o.w = f2bf(v.w);
    int row = i >> 8, col = i & 255;
    int dst = (row << 8) | (col & 192) | ((col & 63) ^ ((row & 7) << 3));
    *(ushort4*)(xb + dst) = o;
}

// ---- prep: MbT[kk][o][i'] = M(kk)[i][o], i pre-swizzled by (o&7)<<3 ----------
__global__ void k_transpose_M(const float* __restrict__ Mp, const float* __restrict__ Mm,
                              unsigned short* __restrict__ MbT) {
    __shared__ float tile[32][33];
    int kk = blockIdx.z;
    const float* src = ((kk < 24) ? Mp : Mm) + (size_t)((kk < 24) ? kk : kk - 24) * 65536;
    int i0 = blockIdx.x * 32, o0 = blockIdx.y * 32;
    int tx = threadIdx.x, ty = threadIdx.y;
    for (int j = 0; j < 4; ++j)
        tile[ty + j * 8][tx] = src[(i0 + ty + j * 8) * 256 + o0 + tx];
    __syncthreads();
    for (int j = 0; j < 4; ++j) {
        int orow = o0 + ty + j * 8, i = i0 + tx;
        int ic = (i & 192) | ((i & 63) ^ ((orow & 7) << 3));
        MbT[(size_t)kk * 65536 + orow * 256 + ic] = f2bf(tile[tx][ty + j * 8]);
    }
}

// ---- prep: ToepA[kk][didx] 128x64 tiles, col pre-swizzled --------------------
// ToepA[kk][didx][i][j'] = sgn*phi[(didx-1)*64 + i - j][k],  j' = j ^ ((i&7)<<3)
__global__ void k_prep_toep(const float* __restrict__ phi, unsigned short* __restrict__ ToepA) {
    int kk = blockIdx.x;           // 48
    int dm = (int)blockIdx.y - 1;  // d64 in [-1, 14]
    int k = (kk < 24) ? kk : kk - 24;
    int tid = threadIdx.x;
    int i = tid >> 1, j0 = (tid & 1) * 32;
    unsigned short* dst = ToepA + ((size_t)kk * 16 + (dm + 1)) * 8192 + i * 64;
    int sw = (i & 7) << 3;
#pragma unroll
    for (int q = 0; q < 8; ++q) {
        int j = j0 + q * 4;
        unsigned short e[4];
#pragma unroll
        for (int ee = 0; ee < 4; ++ee) {
            int t = dm * 64 + i - (j + ee);
            float v = 0.f;
            if (t >= 0 && t < 1024) {
                v = phi[t * 24 + k];
                if (kk >= 24 && (t & 1)) v = -v;
            }
            e[ee] = f2bf(v);
        }
        ushort4 ov; ov.x = e[0]; ov.y = e[1]; ov.z = e[2]; ov.w = e[3];
        *(ushort4*)(dst + (j ^ sw)) = ov;
    }
}

// ---- stage 1: grid (8 m-tiles, 96 = 48kk x 2 o-halves, g batches), 256 thr ---
__global__ __launch_bounds__(256, 2) void k_stage1(const unsigned short* __restrict__ xb0,
                                                   const unsigned short* __restrict__ MbT,
                                                   unsigned short* __restrict__ Z) {
    __shared__ unsigned short lds[2][16384];  // [buf][ A 8192 | B 8192 ]
    int tid = threadIdx.x, lane = tid & 63, w = tid >> 6;
    int wm = w >> 1, wn = w & 1;
    int m0 = blockIdx.x * 128;
    int kk = blockIdx.y >> 1;
    int o0 = (blockIdx.y & 1) * 128;
    int b  = blockIdx.z;
    const unsigned short* xb_b = xb0 + (size_t)b * 262144;
    unsigned short* Zb = Z + (size_t)b * ZB_;
    const unsigned short* Bsrc = MbT + (size_t)kk * 65536;
    int l16 = lane & 15, kofs = (lane >> 4) * 8;
    int sw = (l16 & 7) << 3;
    int r8 = lane >> 3, cg = lane & 7;

    int arow[4], brow[4], lofs[4];
#pragma unroll
    for (int q = 0; q < 4; ++q) {
        int rr = q * 32 + w * 8 + r8;
        arow[q] = (m0 + rr) * 256 + cg * 8;
        brow[q] = (o0 + rr) * 256 + cg * 8;
        lofs[q] = q * 2048 + w * 512;
    }

    f32x4 acc[4][4];
    for (int i = 0; i < 4; ++i)
        for (int j = 0; j < 4; ++j) {
            acc[i][j][0] = 0.f; acc[i][j][1] = 0.f; acc[i][j][2] = 0.f; acc[i][j][3] = 0.f;
        }

#pragma unroll
    for (int q = 0; q < 4; ++q) {
        gl16(xb_b + arow[q], &lds[0][0] + lofs[q]);
        gl16(Bsrc + brow[q], &lds[0][8192] + lofs[q]);
    }
    __syncthreads();

    int buf = 0;
    for (int ko = 0; ko < 4; ++ko) {
        if (ko < 3) {
#pragma unroll
            for (int q = 0; q < 4; ++q) {
                gl16(xb_b + arow[q] + (ko + 1) * 64, &lds[buf ^ 1][0] + lofs[q]);
                gl16(Bsrc + brow[q] + (ko + 1) * 64, &lds[buf ^ 1][8192] + lofs[q]);
            }
        }
        const unsigned short* Abase = &lds[buf][0];
        const unsigned short* Bbase = &lds[buf][8192];
#pragma unroll
        for (int ks = 0; ks < 2; ++ks) {
            int koX = (ks * 32 + kofs) ^ sw;
            bf16x8 af[4], bfv[4];
#pragma unroll
            for (int mi = 0; mi < 4; ++mi)
                af[mi] = *(const bf16x8*)(Abase + (wm * 64 + mi * 16 + l16) * 64 + koX);
#pragma unroll
            for (int ni = 0; ni < 4; ++ni)
                bfv[ni] = *(const bf16x8*)(Bbase + (wn * 64 + ni * 16 + l16) * 64 + koX);
#pragma unroll
            for (int mi = 0; mi < 4; ++mi)
#pragma unroll
                for (int ni = 0; ni < 4; ++ni)
                    acc[mi][ni] = __builtin_amdgcn_mfma_f32_16x16x32_bf16(af[mi], bfv[ni], acc[mi][ni], 0, 0, 0);
        }
        __syncthreads();
        buf ^= 1;
    }

    int r4 = (lane >> 4) * 4;
    for (int mi = 0; mi < 4; ++mi) {
        int sbase = m0 + wm * 64 + mi * 16 + r4;
        for (int ni = 0; ni < 4; ++ni) {
            int o = o0 + wn * 64 + ni * 16 + l16;
            ushort4 pk;
            pk.x = f2bf(acc[mi][ni][0]); pk.y = f2bf(acc[mi][ni][1]);
            pk.z = f2bf(acc[mi][ni][2]); pk.w = f2bf(acc[mi][ni][3]);
            *(ushort4*)(Zb + (size_t)kk * 262144 + (size_t)o * 1024 + (sbase ^ ((o & 7) << 3))) = pk;
        }
    }
}

// ---- stage 2: grid (4 diag-pairs, 2 o-tiles x g batches, kg), 256 thr --------
// Counted-vmcnt pipeline: A 1-ahead (2 bufs), Z 2-ahead (3 bufs). LDS 80 KB.
__global__ __launch_bounds__(256, 2) void k_stage2(const unsigned short* __restrict__ Z,
                                                   const unsigned short* __restrict__ ToepA,
                                                   float* __restrict__ partial, int kkpg) {
    __shared__ unsigned short Abuf[2][8192];
    __shared__ unsigned short Zbuf[3][8192];
    int tid = threadIdx.x, lane = tid & 63, w = tid >> 6;
    int wm = w >> 1, wn = w & 1;

    // XCD-chunked bijective remap (nwg % 8 == 0 always here): contiguous wgid
    // chunks per XCD; pr fastest => the 4 blocks sharing (o,b,kg) co-locate.
    int gy = gridDim.y, nwg = 4 * gy * gridDim.z;
    int orig = blockIdx.x + blockIdx.y * 4 + blockIdx.z * 4 * gy;
    int wg = (orig & 7) * (nwg >> 3) + (orig >> 3);
    int pr = wg & 3;
    int yy = (wg >> 2) % gy;
    int zz = (wg >> 2) / gy;
    int o0 = (yy & 1) * 128;
    int b  = yy >> 1;
    int kgi = zz;
    int kk0 = kgi * kkpg;

    int l16 = lane & 15, kofs = (lane >> 4) * 8;
    int sw = (l16 & 7) << 3;
    int r8 = lane >> 3, cg = lane & 7;

    const unsigned short* Zb = Z + (size_t)b * ZB_;
    float* pb = partial + ((size_t)b * gridDim.z + kgi) * 262144;

    int arow[4], zrow[4], lofs[4];
#pragma unroll
    for (int q = 0; q < 4; ++q) {
        int rr = q * 32 + w * 8 + r8;
        arow[q] = rr * 64 + cg * 8;
        zrow[q] = (o0 + rr) * 1024 + cg * 8;
        lofs[q] = q * 2048 + w * 512;
    }

    for (int half = 0; half < 2; ++half) {
        int lb = half ? (7 - pr) : pr;
        int l0 = lb * 128;
        int nch = 2 * lb + 2;
        int total = kkpg * nch;

        f32x4 acc[4][4];
        for (int i = 0; i < 4; ++i)
            for (int j = 0; j < 4; ++j) {
                acc[i][j][0] = 0.f; acc[i][j][1] = 0.f; acc[i][j][2] = 0.f; acc[i][j][3] = 0.f;
            }

        __syncthreads();   // previous-half readers done before restaging LDS

        auto stageA = [&](int bi, int kka, int didx) {
            const unsigned short* gA = ToepA + ((size_t)kka * 16 + didx) * 8192;
#pragma unroll
            for (int q = 0; q < 4; ++q) gl16(gA + arow[q], &Abuf[bi][0] + lofs[q]);
        };
        auto stageZ = [&](int bi, int kka, int s0) {
            const unsigned short* gZ = Zb + (size_t)kka * 262144 + s0;
#pragma unroll
            for (int q = 0; q < 4; ++q) gl16(gZ + zrow[q], &Zbuf[bi][0] + lofs[q]);
        };
        auto compute = [&](int ba, int bz) {
            const unsigned short* Abase = &Abuf[ba][0];
            const unsigned short* Zbase = &Zbuf[bz][0];
#pragma unroll
            for (int ks = 0; ks < 2; ++ks) {
                int koX = (ks * 32 + kofs) ^ sw;
                bf16x8 af[4], bfv[4];
#pragma unroll
                for (int mi = 0; mi < 4; ++mi)
                    af[mi] = *(const bf16x8*)(Abase + (wm * 64 + mi * 16 + l16) * 64 + koX);
#pragma unroll
                for (int ni = 0; ni < 4; ++ni)
                    bfv[ni] = *(const bf16x8*)(Zbase + (wn * 64 + ni * 16 + l16) * 64 + koX);
#pragma unroll
                for (int mi = 0; mi < 4; ++mi)
#pragma unroll
                    for (int ni = 0; ni < 4; ++ni)
                        acc[mi][ni] = __builtin_amdgcn_mfma_f32_16x16x32_bf16(af[mi], bfv[ni], acc[mi][ni], 0, 0, 0);
            }
        };

        // prologue: A(0), Z(0), Z(1)   [chunk c = (sc=c%nch, kkx=c/nch); nch>=2]
        stageA(0, kk0, 2 * lb + 1);
        stageZ(0, kk0, 0);
        stageZ(1, kk0, 64);

        // rolling coords: A next = chunk 1; Z next = chunk 2
        int scA = 1, kkA = 0;
        int scZ = 2, kkZ = 0;
        if (scZ == nch) { scZ = 0; kkZ = 1; }
        int jz = 2;

        for (int j = 0; j < total - 1; ++j) {
            asm volatile("s_waitcnt vmcnt(4)" ::: "memory");
            __builtin_amdgcn_sched_barrier(0);
            __builtin_amdgcn_s_barrier();
            __builtin_amdgcn_sched_barrier(0);
            // issue A for chunk j+1 (always valid in this loop)
            stageA((j + 1) & 1, kk0 + kkA, 2 * lb - scA + 1);
            ++scA; if (scA == nch) { scA = 0; ++kkA; }
            // issue Z for chunk j+2 (skip past end)
            if (jz < total) {
                stageZ(jz % 3, kk0 + kkZ, scZ * 64);
                ++scZ; if (scZ == nch) { scZ = 0; ++kkZ; }
                ++jz;
            }
            compute(j & 1, j % 3);
        }
        asm volatile("s_waitcnt vmcnt(0)" ::: "memory");
        __builtin_amdgcn_sched_barrier(0);
        __builtin_amdgcn_s_barrier();
        __builtin_amdgcn_sched_barrier(0);
        compute((total - 1) & 1, (total - 1) % 3);

        int r4 = (lane >> 4) * 4;
        for (int mi = 0; mi < 4; ++mi) {
            int l = l0 + wm * 64 + mi * 16 + r4;
            for (int ni = 0; ni < 4; ++ni) {
                int o = o0 + wn * 64 + ni * 16 + l16;
                float* dst = pb + (size_t)l * 256 + o;
                dst[0]   = acc[mi][ni][0];
                dst[256] = acc[mi][ni][1];
                dst[512] = acc[mi][ni][2];
                dst[768] = acc[mi][ni][3];
            }
        }
    }
}

// ---- reduce: out[b][l][o] = sum_kg partial[b][kg][l][o] ----------------------
__global__ void k_reduce(const float* __restrict__ partial, float* __restrict__ outg, int kg) {
    const float* pb = partial + (size_t)blockIdx.y * kg * 262144;
    int i = (blockIdx.x * 256 + threadIdx.x) * 4;
    float4 s = *(const float4*)(pb + i);
    for (int kgi = 1; kgi < kg; ++kgi) {
        float4 v = *(const float4*)(pb + (size_t)kgi * 262144 + i);
        s.x += v.x; s.y += v.y; s.z += v.z; s.w += v.w;
    }
    *(float4*)(outg + (size_t)blockIdx.y * 262144 + i) = s;
}

extern "C" void kernel_launch(void* const* d_in, const int* in_sizes, int n_in,
                              void* d_out, int out_size, void* d_ws, size_t ws_size,
                              hipStream_t stream) {
    const float* x   = (const float*)d_in[0];   // [4,1024,256]
    const float* phi = (const float*)d_in[1];   // [1024,24]
    const float* Mp  = (const float*)d_in[2];   // [24,256,256]
    const float* Mm  = (const float*)d_in[3];   // [24,256,256]
    float* out = (float*)d_out;                 // [4,1024,256]

    char* ws = (char*)d_ws;
    unsigned short* xb    = (unsigned short*)(ws);             //  2,097,152 B
    unsigned short* MbT   = (unsigned short*)(ws + 2097152);   //  6,291,456 B
    unsigned short* ToepA = (unsigned short*)(ws + 8388608);   // 12,582,912 B
    unsigned short* Zbuf  = (unsigned short*)(ws + 20971520);  // g * 25,165,824 B
    const size_t fixed = 20971520;

    // pick batch-group g and split-K kg (prefer 512-block uniform grid: g=4,kg=16)
    int g = 4, kg = 16;
    auto need = [&](int gg, int kk) {
        return fixed + (size_t)gg * 25165824 + (size_t)gg * (size_t)kk * 1048576;
    };
    if (need(4, 16) > ws_size) {
        kg = 12;
        if (need(4, 12) > ws_size) {
            g = 2; kg = 16;
            if (need(2, 16) > ws_size) {
                kg = 12;
                if (need(2, 12) > ws_size) {
                    g = 1; kg = 16;
                    if (need(1, 16) > ws_size) {
                        kg = 12;
                        if (need(1, 12) > ws_size) kg = 6;
                    }
                }
            }
        }
    }
    float* partial = (float*)(ws + fixed + (size_t)g * 25165824);

    k_prep_x<<<dim3(1024), dim3(256), 0, stream>>>(x, xb);
    k_transpose_M<<<dim3(8, 8, 48), dim3(32, 8), 0, stream>>>(Mp, Mm, MbT);
    k_prep_toep<<<dim3(48, 16), dim3(256), 0, stream>>>(phi, ToepA);

    for (int b0 = 0; b0 < 4; b0 += g) {
        k_stage1<<<dim3(8, 96, g), dim3(256), 0, stream>>>(xb + (size_t)b0 * 262144, MbT, Zbuf);
        k_stage2<<<dim3(4, 2 * g, kg), dim3(256), 0, stream>>>(Zbuf, ToepA, partial, 48 / kg);
        k_reduce<<<dim3(256, g), dim3(256), 0, stream>>>(partial, out + (size_t)b0 * 262144, kg);
    }
}

// Round 8
// 147.667 us; speedup vs baseline: 2.9135x; 1.0790x over previous
//
#include <hip/hip_runtime.h>

// MiniSTU: out[b,l,o] = sum_k sum_{s<=l} phi[l-s,k]*(x@Mp[k])[o] + (-1)^(l-s)-weighted Mm term
// Stage 1: Z[b][kk][o][s]  (s pre-swizzled), gl16 counted-vmcnt MFMA GEMM
// Stage 2: 128l x 128o tiles, gl16 counted-vmcnt pipeline (A 1-ahead, Z 2-ahead),
//          XCD-chunked block remap so pr-groups share an XCD's L2 for Z panels.
// All LDS staging: linear dest + pre-swizzled global source + XOR on ds_read.

#define ZB_ 12582912  // Z elems per batch (48*256*1024)

typedef __attribute__((ext_vector_type(8))) short bf16x8;
typedef __attribute__((ext_vector_type(4))) float f32x4;

__device__ inline unsigned short f2bf(float f) {
    unsigned u = __float_as_uint(f);
    u += 0x7FFFu + ((u >> 16) & 1u);   // RNE
    return (unsigned short)(u >> 16);
}

__device__ inline void gl16(const unsigned short* g, unsigned short* l) {
    __builtin_amdgcn_global_load_lds((const __attribute__((address_space(1))) void*)g,
                                     (__attribute__((address_space(3))) void*)l, 16, 0, 0);
}

// ---- merged prep: [0,1024) prep_x | [1024,1792) prep_toep | [1792,4864) transpose_M
__global__ __launch_bounds__(256) void k_prep_all(const float* __restrict__ x,
                                                  const float* __restrict__ phi,
                                                  const float* __restrict__ Mp,
                                                  const float* __restrict__ Mm,
                                                  unsigned short* __restrict__ xb,
                                                  unsigned short* __restrict__ ToepA,
                                                  unsigned short* __restrict__ MbT) {
    __shared__ float tile[32][33];
    int bid = blockIdx.x, tid = threadIdx.x;
    if (bid < 1024) {
        // x (f32) -> xb (bf16), i pre-swizzled within 64-chunks by (s&7)<<3
        int i = (bid * 256 + tid) * 4;
        float4 v = *(const float4*)(x + i);
        ushort4 o;
        o.x = f2bf(v.x); o.y = f2bf(v.y); o.z = f2bf(v.z); o.w = f2bf(v.w);
        int row = i >> 8, col = i & 255;
        int dst = (row << 8) | (col & 192) | ((col & 63) ^ ((row & 7) << 3));
        *(ushort4*)(xb + dst) = o;
    } else if (bid < 1792) {
        // ToepA[kk][didx][i][j'] = sgn*phi[(didx-1)*64+i-j][k], j' = j ^ ((i&7)<<3)
        int r = bid - 1024;
        int kk = r >> 4;
        int dm = (r & 15) - 1;
        int k = (kk < 24) ? kk : kk - 24;
        int i = tid >> 1, j0 = (tid & 1) * 32;
        unsigned short* dst = ToepA + ((size_t)kk * 16 + (dm + 1)) * 8192 + i * 64;
        int sw = (i & 7) << 3;
#pragma unroll
        for (int q = 0; q < 8; ++q) {
            int j = j0 + q * 4;
            unsigned short e[4];
#pragma unroll
            for (int ee = 0; ee < 4; ++ee) {
                int t = dm * 64 + i - (j + ee);
                float v = 0.f;
                if (t >= 0 && t < 1024) {
                    v = phi[t * 24 + k];
                    if (kk >= 24 && (t & 1)) v = -v;
                }
                e[ee] = f2bf(v);
            }
            ushort4 ov; ov.x = e[0]; ov.y = e[1]; ov.z = e[2]; ov.w = e[3];
            *(ushort4*)(dst + (j ^ sw)) = ov;
        }
    } else {
        // MbT[kk][o][i'] = M(kk)[i][o], i pre-swizzled by (o&7)<<3
        int flat = bid - 1792;
        int kk = flat >> 6, rr = flat & 63;
        int i0 = (rr >> 3) * 32, o0 = (rr & 7) * 32;
        int tx = tid & 31, ty = tid >> 5;
        const float* src = ((kk < 24) ? Mp : Mm) + (size_t)((kk < 24) ? kk : kk - 24) * 65536;
        for (int j = 0; j < 4; ++j)
            tile[ty + j * 8][tx] = src[(i0 + ty + j * 8) * 256 + o0 + tx];
        __syncthreads();
        for (int j = 0; j < 4; ++j) {
            int orow = o0 + ty + j * 8, i = i0 + tx;
            int ic = (i & 192) | ((i & 63) ^ ((orow & 7) << 3));
            MbT[(size_t)kk * 65536 + orow * 256 + ic] = f2bf(tile[tx][ty + j * 8]);
        }
    }
}

// ---- stage 1: grid (8 m-tiles, 96 = 48kk x 2 o-halves, g batches), 256 thr ---
// Counted-vmcnt pipeline: A(xb) 2-buf 1-ahead, B(MbT) 3-buf 2-ahead. 4 K-chunks.
__global__ __launch_bounds__(256, 2) void k_stage1(const unsigned short* __restrict__ xb0,
                                                   const unsigned short* __restrict__ MbT,
                                                   unsigned short* __restrict__ Z) {
    __shared__ unsigned short Ab[2][8192];
    __shared__ unsigned short Bb[3][8192];
    int tid = threadIdx.x, lane = tid & 63, w = tid >> 6;
    int wm = w >> 1, wn = w & 1;
    int m0 = blockIdx.x * 128;
    int kk = blockIdx.y >> 1;
    int o0 = (blockIdx.y & 1) * 128;
    int b  = blockIdx.z;
    const unsigned short* xb_b = xb0 + (size_t)b * 262144;
    unsigned short* Zb = Z + (size_t)b * ZB_;
    const unsigned short* Bsrc = MbT + (size_t)kk * 65536;
    int l16 = lane & 15, kofs = (lane >> 4) * 8;
    int sw = (l16 & 7) << 3;
    int r8 = lane >> 3, cg = lane & 7;

    int arow[4], brow[4], lofs[4];
#pragma unroll
    for (int q = 0; q < 4; ++q) {
        int rr = q * 32 + w * 8 + r8;
        arow[q] = (m0 + rr) * 256 + cg * 8;
        brow[q] = (o0 + rr) * 256 + cg * 8;
        lofs[q] = q * 2048 + w * 512;
    }

    f32x4 acc[4][4];
    for (int i = 0; i < 4; ++i)
        for (int j = 0; j < 4; ++j) {
            acc[i][j][0] = 0.f; acc[i][j][1] = 0.f; acc[i][j][2] = 0.f; acc[i][j][3] = 0.f;
        }

    auto stageA = [&](int bi, int ko) {
#pragma unroll
        for (int q = 0; q < 4; ++q) gl16(xb_b + arow[q] + ko * 64, &Ab[bi][0] + lofs[q]);
    };
    auto stageB = [&](int bi, int ko) {
#pragma unroll
        for (int q = 0; q < 4; ++q) gl16(Bsrc + brow[q] + ko * 64, &Bb[bi][0] + lofs[q]);
    };

    // prologue: A(0), B(0), B(1)  -> 12 loads in flight
    stageA(0, 0); stageB(0, 0); stageB(1, 1);

    for (int ko = 0; ko < 4; ++ko) {
        if (ko < 3) { asm volatile("s_waitcnt vmcnt(4)" ::: "memory"); }
        else        { asm volatile("s_waitcnt vmcnt(0)" ::: "memory"); }
        __builtin_amdgcn_sched_barrier(0);
        __builtin_amdgcn_s_barrier();
        __builtin_amdgcn_sched_barrier(0);
        if (ko < 3) stageA((ko + 1) & 1, ko + 1);
        if (ko < 2) stageB((ko + 2) % 3, ko + 2);

        const unsigned short* Abase = &Ab[ko & 1][0];
        const unsigned short* Bbase = &Bb[ko % 3][0];
        __builtin_amdgcn_s_setprio(1);
#pragma unroll
        for (int ks = 0; ks < 2; ++ks) {
            int koX = (ks * 32 + kofs) ^ sw;
            bf16x8 af[4], bfv[4];
#pragma unroll
            for (int mi = 0; mi < 4; ++mi)
                af[mi] = *(const bf16x8*)(Abase + (wm * 64 + mi * 16 + l16) * 64 + koX);
#pragma unroll
            for (int ni = 0; ni < 4; ++ni)
                bfv[ni] = *(const bf16x8*)(Bbase + (wn * 64 + ni * 16 + l16) * 64 + koX);
#pragma unroll
            for (int mi = 0; mi < 4; ++mi)
#pragma unroll
                for (int ni = 0; ni < 4; ++ni)
                    acc[mi][ni] = __builtin_amdgcn_mfma_f32_16x16x32_bf16(af[mi], bfv[ni], acc[mi][ni], 0, 0, 0);
        }
        __builtin_amdgcn_s_setprio(0);
    }

    // store Z with s pre-swizzled by (o&7)<<3 (within 64-chunk; sbase%8 in {0,4})
    int r4 = (lane >> 4) * 4;
    for (int mi = 0; mi < 4; ++mi) {
        int sbase = m0 + wm * 64 + mi * 16 + r4;
        for (int ni = 0; ni < 4; ++ni) {
            int o = o0 + wn * 64 + ni * 16 + l16;
            ushort4 pk;
            pk.x = f2bf(acc[mi][ni][0]); pk.y = f2bf(acc[mi][ni][1]);
            pk.z = f2bf(acc[mi][ni][2]); pk.w = f2bf(acc[mi][ni][3]);
            *(ushort4*)(Zb + (size_t)kk * 262144 + (size_t)o * 1024 + (sbase ^ ((o & 7) << 3))) = pk;
        }
    }
}

// ---- stage 2: grid (4 diag-pairs, 2 o-tiles x g batches, kg), 256 thr --------
// Counted-vmcnt pipeline: A 1-ahead (2 bufs), Z 2-ahead (3 bufs). LDS 80 KB.
__global__ __launch_bounds__(256, 2) void k_stage2(const unsigned short* __restrict__ Z,
                                                   const unsigned short* __restrict__ ToepA,
                                                   float* __restrict__ partial, int kkpg) {
    __shared__ unsigned short Abuf[2][8192];
    __shared__ unsigned short Zbuf[3][8192];
    int tid = threadIdx.x, lane = tid & 63, w = tid >> 6;
    int wm = w >> 1, wn = w & 1;

    // XCD-chunked bijective remap (nwg % 8 == 0 always here)
    int gy = gridDim.y, nwg = 4 * gy * gridDim.z;
    int orig = blockIdx.x + blockIdx.y * 4 + blockIdx.z * 4 * gy;
    int wg = (orig & 7) * (nwg >> 3) + (orig >> 3);
    int pr = wg & 3;
    int yy = (wg >> 2) % gy;
    int zz = (wg >> 2) / gy;
    int o0 = (yy & 1) * 128;
    int b  = yy >> 1;
    int kgi = zz;
    int kk0 = kgi * kkpg;

    int l16 = lane & 15, kofs = (lane >> 4) * 8;
    int sw = (l16 & 7) << 3;
    int r8 = lane >> 3, cg = lane & 7;

    const unsigned short* Zb = Z + (size_t)b * ZB_;
    float* pb = partial + ((size_t)b * gridDim.z + kgi) * 262144;

    int arow[4], zrow[4], lofs[4];
#pragma unroll
    for (int q = 0; q < 4; ++q) {
        int rr = q * 32 + w * 8 + r8;
        arow[q] = rr * 64 + cg * 8;
        zrow[q] = (o0 + rr) * 1024 + cg * 8;
        lofs[q] = q * 2048 + w * 512;
    }

    for (int half = 0; half < 2; ++half) {
        int lb = half ? (7 - pr) : pr;
        int l0 = lb * 128;
        int nch = 2 * lb + 2;
        int total = kkpg * nch;

        f32x4 acc[4][4];
        for (int i = 0; i < 4; ++i)
            for (int j = 0; j < 4; ++j) {
                acc[i][j][0] = 0.f; acc[i][j][1] = 0.f; acc[i][j][2] = 0.f; acc[i][j][3] = 0.f;
            }

        __syncthreads();   // previous-half readers done before restaging LDS

        auto stageA = [&](int bi, int kka, int didx) {
            const unsigned short* gA = ToepA + ((size_t)kka * 16 + didx) * 8192;
#pragma unroll
            for (int q = 0; q < 4; ++q) gl16(gA + arow[q], &Abuf[bi][0] + lofs[q]);
        };
        auto stageZ = [&](int bi, int kka, int s0) {
            const unsigned short* gZ = Zb + (size_t)kka * 262144 + s0;
#pragma unroll
            for (int q = 0; q < 4; ++q) gl16(gZ + zrow[q], &Zbuf[bi][0] + lofs[q]);
        };
        auto compute = [&](int ba, int bz) {
            const unsigned short* Abase = &Abuf[ba][0];
            const unsigned short* Zbase = &Zbuf[bz][0];
            __builtin_amdgcn_s_setprio(1);
#pragma unroll
            for (int ks = 0; ks < 2; ++ks) {
                int koX = (ks * 32 + kofs) ^ sw;
                bf16x8 af[4], bfv[4];
#pragma unroll
                for (int mi = 0; mi < 4; ++mi)
                    af[mi] = *(const bf16x8*)(Abase + (wm * 64 + mi * 16 + l16) * 64 + koX);
#pragma unroll
                for (int ni = 0; ni < 4; ++ni)
                    bfv[ni] = *(const bf16x8*)(Zbase + (wn * 64 + ni * 16 + l16) * 64 + koX);
#pragma unroll
                for (int mi = 0; mi < 4; ++mi)
#pragma unroll
                    for (int ni = 0; ni < 4; ++ni)
                        acc[mi][ni] = __builtin_amdgcn_mfma_f32_16x16x32_bf16(af[mi], bfv[ni], acc[mi][ni], 0, 0, 0);
            }
            __builtin_amdgcn_s_setprio(0);
        };

        // prologue: A(0), Z(0), Z(1)
        stageA(0, kk0, 2 * lb + 1);
        stageZ(0, kk0, 0);
        stageZ(1, kk0, 64);

        int scA = 1, kkA = 0;
        int scZ = 2, kkZ = 0;
        if (scZ == nch) { scZ = 0; kkZ = 1; }
        int jz = 2;

        for (int j = 0; j < total - 1; ++j) {
            asm volatile("s_waitcnt vmcnt(4)" ::: "memory");
            __builtin_amdgcn_sched_barrier(0);
            __builtin_amdgcn_s_barrier();
            __builtin_amdgcn_sched_barrier(0);
            stageA((j + 1) & 1, kk0 + kkA, 2 * lb - scA + 1);
            ++scA; if (scA == nch) { scA = 0; ++kkA; }
            if (jz < total) {
                stageZ(jz % 3, kk0 + kkZ, scZ * 64);
                ++scZ; if (scZ == nch) { scZ = 0; ++kkZ; }
                ++jz;
            }
            compute(j & 1, j % 3);
        }
        asm volatile("s_waitcnt vmcnt(0)" ::: "memory");
        __builtin_amdgcn_sched_barrier(0);
        __builtin_amdgcn_s_barrier();
        __builtin_amdgcn_sched_barrier(0);
        compute((total - 1) & 1, (total - 1) % 3);

        int r4 = (lane >> 4) * 4;
        for (int mi = 0; mi < 4; ++mi) {
            int l = l0 + wm * 64 + mi * 16 + r4;
            for (int ni = 0; ni < 4; ++ni) {
                int o = o0 + wn * 64 + ni * 16 + l16;
                float* dst = pb + (size_t)l * 256 + o;
                dst[0]   = acc[mi][ni][0];
                dst[256] = acc[mi][ni][1];
                dst[512] = acc[mi][ni][2];
                dst[768] = acc[mi][ni][3];
            }
        }
    }
}

// ---- reduce: out[b][l][o] = sum_kg partial[b][kg][l][o] ----------------------
__global__ void k_reduce(const float* __restrict__ partial, float* __restrict__ outg, int kg) {
    const float* pb = partial + (size_t)blockIdx.y * kg * 262144;
    int i = (blockIdx.x * 256 + threadIdx.x) * 4;
    float4 s = *(const float4*)(pb + i);
    for (int kgi = 1; kgi < kg; ++kgi) {
        float4 v = *(const float4*)(pb + (size_t)kgi * 262144 + i);
        s.x += v.x; s.y += v.y; s.z += v.z; s.w += v.w;
    }
    *(float4*)(outg + (size_t)blockIdx.y * 262144 + i) = s;
}

extern "C" void kernel_launch(void* const* d_in, const int* in_sizes, int n_in,
                              void* d_out, int out_size, void* d_ws, size_t ws_size,
                              hipStream_t stream) {
    const float* x   = (const float*)d_in[0];   // [4,1024,256]
    const float* phi = (const float*)d_in[1];   // [1024,24]
    const float* Mp  = (const float*)d_in[2];   // [24,256,256]
    const float* Mm  = (const float*)d_in[3];   // [24,256,256]
    float* out = (float*)d_out;                 // [4,1024,256]

    char* ws = (char*)d_ws;
    unsigned short* xb    = (unsigned short*)(ws);             //  2,097,152 B
    unsigned short* MbT   = (unsigned short*)(ws + 2097152);   //  6,291,456 B
    unsigned short* ToepA = (unsigned short*)(ws + 8388608);   // 12,582,912 B
    unsigned short* Zbuf  = (unsigned short*)(ws + 20971520);  // g * 25,165,824 B
    const size_t fixed = 20971520;

    int g = 4, kg = 16;
    auto need = [&](int gg, int kk) {
        return fixed + (size_t)gg * 25165824 + (size_t)gg * (size_t)kk * 1048576;
    };
    if (need(4, 16) > ws_size) {
        kg = 12;
        if (need(4, 12) > ws_size) {
            g = 2; kg = 16;
            if (need(2, 16) > ws_size) {
                kg = 12;
                if (need(2, 12) > ws_size) {
                    g = 1; kg = 16;
                    if (need(1, 16) > ws_size) {
                        kg = 12;
                        if (need(1, 12) > ws_size) kg = 6;
                    }
                }
            }
        }
    }
    float* partial = (float*)(ws + fixed + (size_t)g * 25165824);

    k_prep_all<<<dim3(4864), dim3(256), 0, stream>>>(x, phi, Mp, Mm, xb, ToepA, MbT);

    for (int b0 = 0; b0 < 4; b0 += g) {
        k_stage1<<<dim3(8, 96, g), dim3(256), 0, stream>>>(xb + (size_t)b0 * 262144, MbT, Zbuf);
        k_stage2<<<dim3(4, 2 * g, kg), dim3(256), 0, stream>>>(Zbuf, ToepA, partial, 48 / kg);
        k_reduce<<<dim3(256, g), dim3(256), 0, stream>>>(partial, out + (size_t)b0 * 262144, kg);
    }
}